// Round 1
// baseline (1203.959 us; speedup 1.0000x reference)
//
#include <hip/hip_runtime.h>
#include <cstdint>
#include <cstddef>

#define B_  4
#define T_  16
#define H_  112
#define W_  112
#define C_  96
#define N_  2048
#define SP_ 8
#define TP_ 4
#define P_  256                 // SP_*SP_*TP_
#define M_  (B_*T_*H_*W_)       // 802816

static_assert(P_ == SP_*SP_*TP_, "patch count");

__device__ __forceinline__ float bflo(unsigned int u){
    union { unsigned int i; float f; } v; v.i = u << 16; return v.f;
}
__device__ __forceinline__ float bfhi(unsigned int u){
    union { unsigned int i; float f; } v; v.i = u & 0xffff0000u; return v.f;
}
__device__ __forceinline__ unsigned short to_bf16(float f){
    union { unsigned int i; float f; } v; v.f = f;
    unsigned int x = v.i;
    return (unsigned short)((x + 0x7fffu + ((x >> 16) & 1u)) >> 16); // RNE
}

// ---- dtype detector: bf16 buffers have sane exponents at even u16 indices;
// fp32 buffers put random mantissa bits there (~16% sane). flag=1 -> bf16.
__global__ void detect_dtype_kernel(const unsigned short* __restrict__ v,
                                    int* __restrict__ flag){
    int lane = threadIdx.x;              // 64 lanes
    unsigned short u = v[lane * 2];
    int e = (u >> 7) & 0xff;
    int sane = ((e >= 107 && e <= 147) || ((u & 0x7fffu) == 0)) ? 1 : 0;
    unsigned long long m = __ballot(sane);
    if (lane == 0) flag[0] = (__popcll(m) >= 48) ? 1 : 0;
}

// ---- b_idx[n] = segment_max(coord[0], seg). Run-compressed atomicMax:
// seg is piecewise-constant in runs (~14 along w), so ~1-2 atomics/thread.
__global__ void segmax_kernel(const int* __restrict__ seg,
                              const int* __restrict__ coord0,
                              int* __restrict__ bidx){
    int g = blockIdx.x * blockDim.x + threadIdx.x;
    int base = g * 8;
    if (base >= M_) return;
    int4 s0 = *(const int4*)(seg + base);
    int4 s1 = *(const int4*)(seg + base + 4);
    int4 c0 = *(const int4*)(coord0 + base);
    int4 c1 = *(const int4*)(coord0 + base + 4);
    int s[8] = {s0.x,s0.y,s0.z,s0.w,s1.x,s1.y,s1.z,s1.w};
    int c[8] = {c0.x,c0.y,c0.z,c0.w,c1.x,c1.y,c1.z,c1.w};
    int cur = s[0], mx = c[0];
    #pragma unroll
    for (int j = 1; j < 8; ++j){
        if (s[j] == cur) { mx = max(mx, c[j]); }
        else { atomicMax(&bidx[cur], mx); cur = s[j]; mx = c[j]; }
    }
    atomicMax(&bidx[cur], mx);
}

// ---- main kernel: one block per segment n, one thread per patch point p.
template<bool BF16>
__global__ __launch_bounds__(P_) void interp_kernel(
    const void* __restrict__ vid_, const int* __restrict__ seg,
    const void* __restrict__ bbox_, const int* __restrict__ bidx,
    const int* __restrict__ flag, void* __restrict__ out_)
{
    if (flag[0] != (BF16 ? 1 : 0)) return;
    const int n = blockIdx.x;
    const int p = threadIdx.x;

    float bb[6];
    if (BF16){
        const unsigned short* bbox = (const unsigned short*)bbox_;
        #pragma unroll
        for (int j = 0; j < 6; ++j) bb[j] = bflo((unsigned int)bbox[j*N_ + n]);
    } else {
        const float* bbox = (const float*)bbox_;
        #pragma unroll
        for (int j = 0; j < 6; ++j) bb[j] = bbox[j*N_ + n];
    }
    const float ymin=bb[0], xmin=bb[1], zmin=bb[2], ymax=bb[3], xmax=bb[4], zmax=bb[5];
    const int b = bidx[n];

    const int pt = p >> 6, ph = (p >> 3) & 7, pw = p & 7;
    const float gt = (float)(pt * (1.0 / (TP_-1)));
    const float gh = (float)(ph * (1.0 / (SP_-1)));
    const float gw = (float)(pw * (1.0 / (SP_-1)));
    const float t_pos = gt * (ymax - ymin) + ymin;
    const float h_pos = gh * (xmax - xmin) + xmin;
    const float w_pos = gw * (zmax - zmin) + zmin;

    int t0 = (int)floorf(t_pos); t0 = min(max(t0, 0), T_-1);
    int h0 = (int)floorf(h_pos); h0 = min(max(h0, 0), H_-1);
    int w0 = (int)floorf(w_pos); w0 = min(max(w0, 0), W_-1);
    const int t1 = min(t0+1, T_-1);
    const int h1 = min(h0+1, H_-1);
    const int w1 = min(w0+1, W_-1);
    const float Ut = t_pos - (float)t0, Uh = h_pos - (float)h0, Uw = w_pos - (float)w0;
    const float Lt = 1.f - Ut, Lh = 1.f - Uh, Lw = 1.f - Uw;

    float wgt[8];
    wgt[0]=Lt*Lh*Lw; wgt[1]=Lt*Lh*Uw; wgt[2]=Lt*Uh*Lw; wgt[3]=Lt*Uh*Uw;
    wgt[4]=Ut*Lh*Lw; wgt[5]=Ut*Lh*Uw; wgt[6]=Ut*Uh*Lw; wgt[7]=Ut*Uh*Uw;

    int idx[8];
    const int r00 = ((b*T_ + t0)*H_ + h0)*W_;
    const int r01 = ((b*T_ + t0)*H_ + h1)*W_;
    const int r10 = ((b*T_ + t1)*H_ + h0)*W_;
    const int r11 = ((b*T_ + t1)*H_ + h1)*W_;
    idx[0]=r00+w0; idx[1]=r00+w1; idx[2]=r01+w0; idx[3]=r01+w1;
    idx[4]=r10+w0; idx[5]=r10+w1; idx[6]=r11+w0; idx[7]=r11+w1;

    // mask: zero-weight corners contribute exactly 0 -> skippable
    float m = 0.f;
    #pragma unroll
    for (int k = 0; k < 8; ++k){
        if (wgt[k] != 0.f) m += wgt[k] * ((seg[idx[k]] == n) ? 1.f : 0.f);
    }

    if (BF16){
        const unsigned short* vid = (const unsigned short*)vid_;
        unsigned short* out = (unsigned short*)out_;
        #pragma unroll 1
        for (int c0 = 0; c0 < C_; c0 += 8){
            float acc[8] = {0.f,0.f,0.f,0.f,0.f,0.f,0.f,0.f};
            #pragma unroll
            for (int k = 0; k < 8; ++k){
                const float w = wgt[k];
                if (w != 0.f){
                    const uint4 raw = *(const uint4*)(vid + (size_t)idx[k]*C_ + c0);
                    acc[0] += w * bflo(raw.x); acc[1] += w * bfhi(raw.x);
                    acc[2] += w * bflo(raw.y); acc[3] += w * bfhi(raw.y);
                    acc[4] += w * bflo(raw.z); acc[5] += w * bfhi(raw.z);
                    acc[6] += w * bflo(raw.w); acc[7] += w * bfhi(raw.w);
                }
            }
            const size_t ob = ((size_t)n*C_ + c0)*P_ + p;
            #pragma unroll
            for (int j = 0; j < 8; ++j) out[ob + (size_t)j*P_] = to_bf16(acc[j]);
        }
        out[(size_t)N_*C_*P_ + (size_t)n*P_ + p] = to_bf16(m);
    } else {
        const float* vid = (const float*)vid_;
        float* out = (float*)out_;
        #pragma unroll 1
        for (int c0 = 0; c0 < C_; c0 += 4){
            float acc[4] = {0.f,0.f,0.f,0.f};
            #pragma unroll
            for (int k = 0; k < 8; ++k){
                const float w = wgt[k];
                if (w != 0.f){
                    const float4 raw = *(const float4*)(vid + (size_t)idx[k]*C_ + c0);
                    acc[0] += w*raw.x; acc[1] += w*raw.y; acc[2] += w*raw.z; acc[3] += w*raw.w;
                }
            }
            const size_t ob = ((size_t)n*C_ + c0)*P_ + p;
            #pragma unroll
            for (int j = 0; j < 4; ++j) out[ob + (size_t)j*P_] = acc[j];
        }
        out[(size_t)N_*C_*P_ + (size_t)n*P_ + p] = m;
    }
}

extern "C" void kernel_launch(void* const* d_in, const int* in_sizes, int n_in,
                              void* d_out, int out_size, void* d_ws, size_t ws_size,
                              hipStream_t stream){
    const void* vid   = d_in[0];
    const int*  seg   = (const int*)d_in[1];
    const int*  coord = (const int*)d_in[2];   // coord[0] = first M_ elements
    const void* bbox  = d_in[3];

    int* flag = (int*)d_ws;
    int* bidx = flag + 64;

    hipMemsetAsync(d_ws, 0, (64 + N_) * sizeof(int), stream);
    detect_dtype_kernel<<<1, 64, 0, stream>>>((const unsigned short*)vid, flag);
    segmax_kernel<<<(M_/8 + 255)/256, 256, 0, stream>>>(seg, coord, bidx);
    interp_kernel<true ><<<N_, P_, 0, stream>>>(vid, seg, bbox, bidx, flag, d_out);
    interp_kernel<false><<<N_, P_, 0, stream>>>(vid, seg, bbox, bidx, flag, d_out);
}